// Round 3
// baseline (105.908 us; speedup 1.0000x reference)
//
#include <hip/hip_runtime.h>

// FactoredBlock: out[n,:] = sum_{k in row n} values[k] * weights[f_table[active_idx[k]], :]
// batch_idx sorted. Two-phase:
//   build_kernel: CSR offsets[N+1] + fused (f, value) pairs -> d_ws
//   gemm_kernel:  1 row per 256-thread block; 4 waves split the row's nnz
//                 (~8 each), 8 independent float4 weight loads in flight per
//                 wave, LDS cross-wave reduction. Weights (768 KB) L2-resident.

#define OUT_COLS 256
#define BLOCK_THREADS 256

// ---------------- phase A: offsets + pairs ----------------
__global__ __launch_bounds__(256)
void build_kernel(const int* __restrict__ batch_idx,
                  const int* __restrict__ active_idx,
                  const float* __restrict__ values,
                  const int* __restrict__ f_table,
                  int* __restrict__ offsets,      // [N+1]
                  int2* __restrict__ pairs,       // [nnz] {f, bits(v)}
                  int nnz, int N)
{
    const int k = blockIdx.x * blockDim.x + threadIdx.x;
    if (k >= nnz) return;
    const int r  = batch_idx[k];
    const int rp = (k == 0) ? -1 : batch_idx[k - 1];
    for (int row = rp + 1; row <= r; ++row) offsets[row] = k;   // lower_bound fill
    if (k == nnz - 1)
        for (int row = r + 1; row <= N; ++row) offsets[row] = nnz;
    pairs[k] = make_int2(f_table[active_idx[k]], __float_as_int(values[k]));
}

// ---------------- phase B: accumulate (1 row / block, 4 waves / row) ----------------
__global__ __launch_bounds__(BLOCK_THREADS, 8)
void gemm_kernel(const int* __restrict__ offsets,
                 const int2* __restrict__ pairs,
                 const float* __restrict__ weights,
                 float* __restrict__ out, int N)
{
    __shared__ float4 partial[3][64];

    const int lane = threadIdx.x & 63;
    const int wave = threadIdx.x >> 6;
    const int row  = blockIdx.x;

    // block-uniform bounds -> scalar loads downstream
    const int start = __builtin_amdgcn_readfirstlane(offsets[row]);
    const int end   = __builtin_amdgcn_readfirstlane(offsets[row + 1]);

    float4 acc = make_float4(0.f, 0.f, 0.f, 0.f);
    const float* __restrict__ wbase = weights + (lane << 2);

    // wave w takes chunks [start + w*8 + 32*i, +8); avg row (~32 nnz) = 1 chunk/wave
    for (int k0 = start + wave * 8; k0 < end; k0 += 32) {
        const int cnt = min(end - k0, 8);
        if (cnt == 8) {
            int2 p[8];
#pragma unroll
            for (int j = 0; j < 8; ++j) p[j] = pairs[k0 + j];
            float4 w[8];
#pragma unroll
            for (int j = 0; j < 8; ++j)
                w[j] = *(const float4*)(wbase + p[j].x * OUT_COLS);
#pragma unroll
            for (int j = 0; j < 8; ++j) {
                const float v = __int_as_float(p[j].y);
                acc.x = fmaf(v, w[j].x, acc.x);
                acc.y = fmaf(v, w[j].y, acc.y);
                acc.z = fmaf(v, w[j].z, acc.z);
                acc.w = fmaf(v, w[j].w, acc.w);
            }
        } else {
            for (int j = 0; j < cnt; ++j) {
                const int2 p = pairs[k0 + j];
                const float v = __int_as_float(p.y);
                const float4 w = *(const float4*)(wbase + p.x * OUT_COLS);
                acc.x = fmaf(v, w.x, acc.x);
                acc.y = fmaf(v, w.y, acc.y);
                acc.z = fmaf(v, w.z, acc.z);
                acc.w = fmaf(v, w.w, acc.w);
            }
        }
    }

    if (wave != 0) partial[wave - 1][lane] = acc;
    __syncthreads();
    if (wave == 0) {
        const float4 p0 = partial[0][lane];
        const float4 p1 = partial[1][lane];
        const float4 p2 = partial[2][lane];
        acc.x += p0.x + p1.x + p2.x;
        acc.y += p0.y + p1.y + p2.y;
        acc.z += p0.z + p1.z + p2.z;
        acc.w += p0.w + p1.w + p2.w;
        *(float4*)(out + row * OUT_COLS + (lane << 2)) = acc;
    }
}

// ---------------- fallback (binary search), used only if ws too small ----------------
__global__ __launch_bounds__(256, 8)
void fallback_kernel(const int* __restrict__ batch_idx,
                     const int* __restrict__ active_idx,
                     const float* __restrict__ values,
                     const int* __restrict__ f_table,
                     const float* __restrict__ weights,
                     float* __restrict__ out,
                     int nnz, int N)
{
    const int wave = threadIdx.x >> 6;
    const int lane = threadIdx.x & 63;
    const int row  = blockIdx.x * 4 + wave;
    if (row >= N) return;

    int lo1 = 0, hi1 = nnz, lo2 = 0, hi2 = nnz;
    while ((lo1 < hi1) | (lo2 < hi2)) {
        if (lo1 < hi1) { int m = (lo1 + hi1) >> 1; if (batch_idx[m] < row) lo1 = m + 1; else hi1 = m; }
        if (lo2 < hi2) { int m = (lo2 + hi2) >> 1; if (batch_idx[m] < row + 1) lo2 = m + 1; else hi2 = m; }
    }
    float4 acc = make_float4(0.f, 0.f, 0.f, 0.f);
    const float* __restrict__ wcol = weights + (lane << 2);
    for (int base = lo1; base < lo2; base += 64) {
        const int cnt = min(lo2 - base, 64);
        float v_l = 0.f; int f_l = 0;
        if (lane < cnt) { const int k = base + lane; v_l = values[k]; f_l = f_table[active_idx[k]]; }
        for (int j = 0; j < cnt; ++j) {
            const float v = __shfl(v_l, j);
            const int   f = __shfl(f_l, j);
            const float4 w = *(const float4*)(wcol + f * OUT_COLS);
            acc.x = fmaf(v, w.x, acc.x);
            acc.y = fmaf(v, w.y, acc.y);
            acc.z = fmaf(v, w.z, acc.z);
            acc.w = fmaf(v, w.w, acc.w);
        }
    }
    *(float4*)(out + row * OUT_COLS + (lane << 2)) = acc;
}

extern "C" void kernel_launch(void* const* d_in, const int* in_sizes, int n_in,
                              void* d_out, int out_size, void* d_ws, size_t ws_size,
                              hipStream_t stream) {
    const int*   batch_idx  = (const int*)d_in[0];
    const int*   active_idx = (const int*)d_in[1];
    const float* values     = (const float*)d_in[2];
    const int*   f_table    = (const int*)d_in[3];
    const float* weights    = (const float*)d_in[4];
    float*       out        = (float*)d_out;

    const int nnz = in_sizes[0];
    const int N   = out_size / OUT_COLS;  // 16384

    const size_t off_bytes  = (size_t)(N + 1) * sizeof(int);
    const size_t pairs_off  = (off_bytes + 15) & ~(size_t)15;
    const size_t need_bytes = pairs_off + (size_t)nnz * sizeof(int2);

    if (ws_size >= need_bytes) {
        int*  offsets = (int*)d_ws;
        int2* pairs   = (int2*)((char*)d_ws + pairs_off);
        const int grid_nnz = (nnz + 255) / 256;
        build_kernel<<<grid_nnz, 256, 0, stream>>>(batch_idx, active_idx, values,
                                                   f_table, offsets, pairs, nnz, N);
        gemm_kernel<<<N, BLOCK_THREADS, 0, stream>>>(offsets, pairs, weights, out, N);
    } else {
        fallback_kernel<<<(N + 3) / 4, 256, 0, stream>>>(
            batch_idx, active_idx, values, f_table, weights, out, nnz, N);
    }
}

// Round 4
// 95.984 us; speedup vs baseline: 1.1034x; 1.1034x over previous
//
#include <hip/hip_runtime.h>

// FactoredBlock: out[n,:] = sum_{k in row n} values[k] * weights[f_table[active_idx[k]], :]
// batch_idx sorted. Three tiny phases:
//   conv_kernel : weights f32 -> bf16 (768 KB -> 384 KB, L2-resident)
//   build_kernel: CSR offsets[N+1] + packed pairs u32 {f:16 | bf16(v):16}
//   gemm_kernel : 1 wave/row (round-2 shape), unroll-16 -> 16 independent
//                 8 B bf16x4 weight loads in flight per wave.

#define OUT_COLS 256
#define WAVES_PER_BLOCK 4
#define BLOCK_THREADS (WAVES_PER_BLOCK * 64)
#define NW (768 * 256)   // weight elements

__device__ __forceinline__ float bf2f(unsigned u) {
    return __int_as_float((int)(u << 16));
}
__device__ __forceinline__ unsigned f2bf(float x) {   // RTN-even
    unsigned u = __float_as_uint(x);
    return (u + 0x7fffu + ((u >> 16) & 1u)) >> 16;
}

// ---------------- phase 0: weights f32 -> bf16 ----------------
__global__ __launch_bounds__(256)
void conv_kernel(const float* __restrict__ w, unsigned short* __restrict__ wbf, int n) {
    const int i = blockIdx.x * 256 + threadIdx.x;
    if (i < n) wbf[i] = (unsigned short)f2bf(w[i]);
}

// ---------------- phase A: offsets + packed pairs ----------------
__global__ __launch_bounds__(256)
void build_kernel(const int* __restrict__ batch_idx,
                  const int* __restrict__ active_idx,
                  const float* __restrict__ values,
                  const int* __restrict__ f_table,
                  int* __restrict__ offsets,            // [N+1]
                  unsigned* __restrict__ pairs,         // [nnz]
                  int nnz, int N)
{
    const int k = blockIdx.x * blockDim.x + threadIdx.x;
    if (k >= nnz) return;
    const int r  = batch_idx[k];
    const int rp = (k == 0) ? -1 : batch_idx[k - 1];
    for (int row = rp + 1; row <= r; ++row) offsets[row] = k;   // lower_bound fill
    if (k == nnz - 1)
        for (int row = r + 1; row <= N; ++row) offsets[row] = nnz;
    const unsigned f = (unsigned)f_table[active_idx[k]];        // < 768
    pairs[k] = (f << 16) | f2bf(values[k]);
}

// ---------------- phase B: accumulate (1 wave / row, unroll-16) ----------------
__global__ __launch_bounds__(BLOCK_THREADS, 8)
void gemm_kernel(const int* __restrict__ offsets,
                 const unsigned* __restrict__ pairs,
                 const unsigned short* __restrict__ wbf,
                 float* __restrict__ out, int N)
{
    const int lane = threadIdx.x & 63;
    const int row  = blockIdx.x * WAVES_PER_BLOCK + (threadIdx.x >> 6);
    if (row >= N) return;

    // wave-uniform bounds -> scalar pair loads downstream
    const int start = __builtin_amdgcn_readfirstlane(offsets[row]);
    const int end   = __builtin_amdgcn_readfirstlane(offsets[row + 1]);

    float4 acc = make_float4(0.f, 0.f, 0.f, 0.f);
    const unsigned short* __restrict__ wbase = wbf + (lane << 2);

    int k = start;
    for (; k + 16 <= end; k += 16) {
        unsigned p[16];
#pragma unroll
        for (int j = 0; j < 16; ++j) p[j] = pairs[k + j];
        ushort4 w[16];
#pragma unroll
        for (int j = 0; j < 16; ++j)
            w[j] = *(const ushort4*)(wbase + (p[j] >> 16) * OUT_COLS);
#pragma unroll
        for (int j = 0; j < 16; ++j) {
            const float v = bf2f(p[j] & 0xffffu);
            acc.x = fmaf(v, bf2f(w[j].x), acc.x);
            acc.y = fmaf(v, bf2f(w[j].y), acc.y);
            acc.z = fmaf(v, bf2f(w[j].z), acc.z);
            acc.w = fmaf(v, bf2f(w[j].w), acc.w);
        }
    }
    for (; k < end; ++k) {
        const unsigned p = pairs[k];
        const float v = bf2f(p & 0xffffu);
        const ushort4 w = *(const ushort4*)(wbase + (p >> 16) * OUT_COLS);
        acc.x = fmaf(v, bf2f(w.x), acc.x);
        acc.y = fmaf(v, bf2f(w.y), acc.y);
        acc.z = fmaf(v, bf2f(w.z), acc.z);
        acc.w = fmaf(v, bf2f(w.w), acc.w);
    }

    *(float4*)(out + row * OUT_COLS + (lane << 2)) = acc;
}

// ---------------- fallback (binary search, f32 weights), if ws too small ----------------
__global__ __launch_bounds__(256, 8)
void fallback_kernel(const int* __restrict__ batch_idx,
                     const int* __restrict__ active_idx,
                     const float* __restrict__ values,
                     const int* __restrict__ f_table,
                     const float* __restrict__ weights,
                     float* __restrict__ out,
                     int nnz, int N)
{
    const int wave = threadIdx.x >> 6;
    const int lane = threadIdx.x & 63;
    const int row  = blockIdx.x * 4 + wave;
    if (row >= N) return;

    int lo1 = 0, hi1 = nnz, lo2 = 0, hi2 = nnz;
    while ((lo1 < hi1) | (lo2 < hi2)) {
        if (lo1 < hi1) { int m = (lo1 + hi1) >> 1; if (batch_idx[m] < row) lo1 = m + 1; else hi1 = m; }
        if (lo2 < hi2) { int m = (lo2 + hi2) >> 1; if (batch_idx[m] < row + 1) lo2 = m + 1; else hi2 = m; }
    }
    float4 acc = make_float4(0.f, 0.f, 0.f, 0.f);
    const float* __restrict__ wcol = weights + (lane << 2);
    for (int base = lo1; base < lo2; base += 64) {
        const int cnt = min(lo2 - base, 64);
        float v_l = 0.f; int f_l = 0;
        if (lane < cnt) { const int k = base + lane; v_l = values[k]; f_l = f_table[active_idx[k]]; }
        for (int j = 0; j < cnt; ++j) {
            const float v = __shfl(v_l, j);
            const int   f = __shfl(f_l, j);
            const float4 w = *(const float4*)(wcol + f * OUT_COLS);
            acc.x = fmaf(v, w.x, acc.x);
            acc.y = fmaf(v, w.y, acc.y);
            acc.z = fmaf(v, w.z, acc.z);
            acc.w = fmaf(v, w.w, acc.w);
        }
    }
    *(float4*)(out + row * OUT_COLS + (lane << 2)) = acc;
}

extern "C" void kernel_launch(void* const* d_in, const int* in_sizes, int n_in,
                              void* d_out, int out_size, void* d_ws, size_t ws_size,
                              hipStream_t stream) {
    const int*   batch_idx  = (const int*)d_in[0];
    const int*   active_idx = (const int*)d_in[1];
    const float* values     = (const float*)d_in[2];
    const int*   f_table    = (const int*)d_in[3];
    const float* weights    = (const float*)d_in[4];
    float*       out        = (float*)d_out;

    const int nnz = in_sizes[0];
    const int N   = out_size / OUT_COLS;  // 16384

    // ws layout: offsets[N+1] | wbf[NW] bf16 | pairs[nnz] u32, 16B-aligned each
    const size_t off_bytes = (size_t)(N + 1) * sizeof(int);
    const size_t wbf_off   = (off_bytes + 15) & ~(size_t)15;
    const size_t pairs_off = (wbf_off + (size_t)NW * 2 + 15) & ~(size_t)15;
    const size_t need      = pairs_off + (size_t)nnz * sizeof(unsigned);

    const int grid_rows = (N + WAVES_PER_BLOCK - 1) / WAVES_PER_BLOCK;

    if (ws_size >= need) {
        int*            offsets = (int*)d_ws;
        unsigned short* wbf     = (unsigned short*)((char*)d_ws + wbf_off);
        unsigned*       pairs   = (unsigned*)((char*)d_ws + pairs_off);

        conv_kernel<<<(NW + 255) / 256, 256, 0, stream>>>(weights, wbf, NW);
        build_kernel<<<(nnz + 255) / 256, 256, 0, stream>>>(
            batch_idx, active_idx, values, f_table, offsets, pairs, nnz, N);
        gemm_kernel<<<grid_rows, BLOCK_THREADS, 0, stream>>>(offsets, pairs, wbf, out, N);
    } else {
        fallback_kernel<<<grid_rows, 256, 0, stream>>>(
            batch_idx, active_idx, values, f_table, weights, out, nnz, N);
    }
}

// Round 5
// 89.279 us; speedup vs baseline: 1.1863x; 1.0751x over previous
//
#include <hip/hip_runtime.h>
#include <hip/hip_fp16.h>

// FactoredBlock: out[n,:] = sum_{k in row n} values[k] * weights[f_table[active_idx[k]], :]
// batch_idx sorted. Two dispatches:
//   build_kernel: fused (weights f32->f16) + CSR offsets[N+1] + packed pairs
//                 u32 {f:16 | f16bits(v):16}
//   gemm_kernel : 1 wave/row. KEY: one 16 B/lane load serves TWO nnz
//                 (lanes 0-31 -> nnz j's weight row, lanes 32-63 -> nnz j+1's)
//                 halving vmem instruction count (TA-throughput bound, ~16cyc/instr);
//                 v_pk_fma_f16 accumulate, shfl_xor(32) combine, f32 store.

#define OUT_COLS 256
#define WAVES_PER_BLOCK 4
#define BLOCK_THREADS (WAVES_PER_BLOCK * 64)
#define NW (768 * 256)   // weight elements

// ---------------- phase A: convert weights + offsets + packed pairs ----------------
__global__ __launch_bounds__(256)
void build_kernel(const int* __restrict__ batch_idx,
                  const int* __restrict__ active_idx,
                  const float* __restrict__ values,
                  const int* __restrict__ f_table,
                  const float* __restrict__ weights,
                  int* __restrict__ offsets,            // [N+1]
                  unsigned* __restrict__ pairs,         // [nnz]
                  __half* __restrict__ wh,              // [NW]
                  int nnz, int N)
{
    const int k = blockIdx.x * 256 + threadIdx.x;
    if (k < NW) wh[k] = __float2half(weights[k]);
    if (k >= nnz) return;
    const int r  = batch_idx[k];
    const int rp = (k == 0) ? -1 : batch_idx[k - 1];
    for (int row = rp + 1; row <= r; ++row) offsets[row] = k;   // lower_bound fill
    if (k == nnz - 1)
        for (int row = r + 1; row <= N; ++row) offsets[row] = nnz;
    const unsigned f = (unsigned)f_table[active_idx[k]];        // < 768
    pairs[k] = (f << 16) | (unsigned)__half_as_ushort(__float2half(values[k]));
}

// ---------------- phase B: accumulate (1 wave/row, 2 nnz per weight load) ----------------
__global__ __launch_bounds__(BLOCK_THREADS, 8)
void gemm_kernel(const int* __restrict__ offsets,
                 const unsigned* __restrict__ pairs,
                 const __half* __restrict__ wh,
                 float* __restrict__ out, int N)
{
    const int lane = threadIdx.x & 63;
    const int row  = blockIdx.x * WAVES_PER_BLOCK + (threadIdx.x >> 6);
    if (row >= N) return;

    // wave-uniform bounds -> scalar pair loads downstream
    const int start = __builtin_amdgcn_readfirstlane(offsets[row]);
    const int end   = __builtin_amdgcn_readfirstlane(offsets[row + 1]);

    const __half2 zero = __float2half2_rn(0.0f);
    __half2 acc0 = zero, acc1 = zero, acc2 = zero, acc3 = zero;

    // lane (l&31) owns cols (l&31)*8 .. +8; lanes<32 take even nnz, lanes>=32 odd
    const __half* __restrict__ wbase = wh + ((lane & 31) << 3);
    const bool lo_half = (lane < 32);

    for (int k = start; k < end; k += 16) {
        unsigned p[16];
#pragma unroll
        for (int j = 0; j < 16; ++j) {
            const unsigned raw = pairs[k + j];        // safe over-read inside ws
            p[j] = (k + j < end) ? raw : 0u;          // scalar cselect; v=0 kills term
        }
        uint4 w[8];
#pragma unroll
        for (int b = 0; b < 8; ++b) {
            const int f0 = (int)(p[2 * b] >> 16);
            const int f1 = (int)(p[2 * b + 1] >> 16);
            const int f  = lo_half ? f0 : f1;         // one cndmask
            w[b] = *(const uint4*)(wbase + (f << 8)); // 16 B: 8 cols of f16
        }
#pragma unroll
        for (int b = 0; b < 8; ++b) {
            unsigned vv0 = p[2 * b] & 0xffffu;       vv0 |= vv0 << 16;
            unsigned vv1 = p[2 * b + 1] & 0xffffu;   vv1 |= vv1 << 16;
            const unsigned vvu = lo_half ? vv0 : vv1;
            const __half2 vv = *(const __half2*)&vvu;
            const __half2* w2 = (const __half2*)&w[b];
            acc0 = __hfma2(w2[0], vv, acc0);
            acc1 = __hfma2(w2[1], vv, acc1);
            acc2 = __hfma2(w2[2], vv, acc2);
            acc3 = __hfma2(w2[3], vv, acc3);
        }
    }

    // combine even/odd halves: lane l and l+32 hold the same 8 cols
    __half2 accs[4] = {acc0, acc1, acc2, acc3};
#pragma unroll
    for (int i = 0; i < 4; ++i) {
        int a = *(const int*)&accs[i];
        const int b = __shfl_xor(a, 32);
        accs[i] = __hadd2(accs[i], *(const __half2*)&b);
    }
    if (lo_half) {
        float4 o0, o1;
        o0.x = __low2float(accs[0]); o0.y = __high2float(accs[0]);
        o0.z = __low2float(accs[1]); o0.w = __high2float(accs[1]);
        o1.x = __low2float(accs[2]); o1.y = __high2float(accs[2]);
        o1.z = __low2float(accs[3]); o1.w = __high2float(accs[3]);
        float* orow = out + row * OUT_COLS + (lane << 3);
        *(float4*)orow = o0;
        *(float4*)(orow + 4) = o1;
    }
}

// ---------------- fallback (binary search, f32 weights), if ws too small ----------------
__global__ __launch_bounds__(256, 8)
void fallback_kernel(const int* __restrict__ batch_idx,
                     const int* __restrict__ active_idx,
                     const float* __restrict__ values,
                     const int* __restrict__ f_table,
                     const float* __restrict__ weights,
                     float* __restrict__ out,
                     int nnz, int N)
{
    const int wave = threadIdx.x >> 6;
    const int lane = threadIdx.x & 63;
    const int row  = blockIdx.x * 4 + wave;
    if (row >= N) return;

    int lo1 = 0, hi1 = nnz, lo2 = 0, hi2 = nnz;
    while ((lo1 < hi1) | (lo2 < hi2)) {
        if (lo1 < hi1) { int m = (lo1 + hi1) >> 1; if (batch_idx[m] < row) lo1 = m + 1; else hi1 = m; }
        if (lo2 < hi2) { int m = (lo2 + hi2) >> 1; if (batch_idx[m] < row + 1) lo2 = m + 1; else hi2 = m; }
    }
    float4 acc = make_float4(0.f, 0.f, 0.f, 0.f);
    const float* __restrict__ wcol = weights + (lane << 2);
    for (int base = lo1; base < lo2; base += 64) {
        const int cnt = min(lo2 - base, 64);
        float v_l = 0.f; int f_l = 0;
        if (lane < cnt) { const int k = base + lane; v_l = values[k]; f_l = f_table[active_idx[k]]; }
        for (int j = 0; j < cnt; ++j) {
            const float v = __shfl(v_l, j);
            const int   f = __shfl(f_l, j);
            const float4 w = *(const float4*)(wcol + f * OUT_COLS);
            acc.x = fmaf(v, w.x, acc.x);
            acc.y = fmaf(v, w.y, acc.y);
            acc.z = fmaf(v, w.z, acc.z);
            acc.w = fmaf(v, w.w, acc.w);
        }
    }
    *(float4*)(out + row * OUT_COLS + (lane << 2)) = acc;
}

extern "C" void kernel_launch(void* const* d_in, const int* in_sizes, int n_in,
                              void* d_out, int out_size, void* d_ws, size_t ws_size,
                              hipStream_t stream) {
    const int*   batch_idx  = (const int*)d_in[0];
    const int*   active_idx = (const int*)d_in[1];
    const float* values     = (const float*)d_in[2];
    const int*   f_table    = (const int*)d_in[3];
    const float* weights    = (const float*)d_in[4];
    float*       out        = (float*)d_out;

    const int nnz = in_sizes[0];
    const int N   = out_size / OUT_COLS;  // 16384

    // ws layout: offsets[N+1] | wh[NW] f16 | pairs[nnz] u32 | 64 B over-read slack
    const size_t off_bytes = (size_t)(N + 1) * sizeof(int);
    const size_t wh_off    = (off_bytes + 15) & ~(size_t)15;
    const size_t pairs_off = (wh_off + (size_t)NW * 2 + 15) & ~(size_t)15;
    const size_t need      = pairs_off + (size_t)nnz * sizeof(unsigned) + 64;

    const int grid_rows = (N + WAVES_PER_BLOCK - 1) / WAVES_PER_BLOCK;

    if (ws_size >= need) {
        int*      offsets = (int*)d_ws;
        __half*   wh      = (__half*)((char*)d_ws + wh_off);
        unsigned* pairs   = (unsigned*)((char*)d_ws + pairs_off);

        const int work = (nnz > NW) ? nnz : NW;
        build_kernel<<<(work + 255) / 256, 256, 0, stream>>>(
            batch_idx, active_idx, values, f_table, weights,
            offsets, pairs, wh, nnz, N);
        gemm_kernel<<<grid_rows, BLOCK_THREADS, 0, stream>>>(offsets, pairs, wh, out, N);
    } else {
        fallback_kernel<<<grid_rows, 256, 0, stream>>>(
            batch_idx, active_idx, values, f_table, weights, out, nnz, N);
    }
}